// Round 1
// baseline (376.077 us; speedup 1.0000x reference)
//
#include <hip/hip_runtime.h>
#include <math.h>

#define T_SEQ 2048
#define NH    12
#define NB    2
#define D_DIM 64
#define R_DIM 16
#define D_STDC 48
#define BHC   (NB*NH)        // 24
#define BQ    64
#define BK    64
#define NQT   (T_SEQ/BQ)     // 32

// ---------------- prep: build Q_aug / K_aug with scales folded in ----------------
// Q_aug[t] = [sqrt(w_std)*Q[t,0:48], sqrt(w_rec)*(K[t]·W)]
// K_aug[t] = [sqrt(w_std)*K[t,0:48], sqrt(w_rec)*(Q[t]·W)]
__global__ __launch_bounds__(256) void prep_kernel(
    const float* __restrict__ Q, const float* __restrict__ K,
    const float* __restrict__ W, const float* __restrict__ wstd,
    const float* __restrict__ wrec,
    float* __restrict__ Qa, float* __restrict__ Ka)
{
  __shared__ float Ws[D_DIM][R_DIM];   // W[d][r]
  __shared__ float Qs[64][65];         // +1 pad -> conflict-free strided reads
  __shared__ float Ks[64][65];
  __shared__ float Lq[64][R_DIM];
  __shared__ float Lk[64][R_DIM];

  const int tid = threadIdx.x;
  const long row0 = (long)blockIdx.x * 64;          // flat (b,h,t) row
  const int h = (int)((row0 / T_SEQ) % NH);         // 64 | T_SEQ so block is h-uniform

  for (int i = tid; i < D_DIM * R_DIM; i += 256) Ws[i / R_DIM][i % R_DIM] = W[i];
  for (int i = tid; i < 64 * D_DIM; i += 256) {
    int r = i >> 6, c = i & 63;
    Qs[r][c] = Q[row0 * D_DIM + i];
    Ks[r][c] = K[row0 * D_DIM + i];
  }
  __syncthreads();

  // each row handled by 4 threads, each doing a 16-wide d-slice
  const int r = tid >> 2, part = tid & 3;
  float ql[R_DIM], kl[R_DIM];
#pragma unroll
  for (int j = 0; j < R_DIM; j++) { ql[j] = 0.f; kl[j] = 0.f; }
#pragma unroll
  for (int dd = 0; dd < 16; dd++) {
    int d = part * 16 + dd;
    float qv = Qs[r][d], kv = Ks[r][d];
#pragma unroll
    for (int j = 0; j < R_DIM; j++) { ql[j] += qv * Ws[d][j]; kl[j] += kv * Ws[d][j]; }
  }
#pragma unroll
  for (int m = 1; m <= 2; m <<= 1) {
#pragma unroll
    for (int j = 0; j < R_DIM; j++) {
      ql[j] += __shfl_xor(ql[j], m, 64);
      kl[j] += __shfl_xor(kl[j], m, 64);
    }
  }
  if (part == 0) {
#pragma unroll
    for (int j = 0; j < R_DIM; j++) { Lq[r][j] = ql[j]; Lk[r][j] = kl[j]; }
  }
  __syncthreads();

  const float sstd = sqrtf(wstd[h]);
  const float srec = sqrtf(wrec[h]);
  for (int i = tid; i < 64 * D_DIM; i += 256) {   // coalesced b32 stores
    int rr = i >> 6, c = i & 63;
    float qa, ka;
    if (c < D_STDC) { qa = sstd * Qs[rr][c]; ka = sstd * Ks[rr][c]; }
    else            { qa = srec * Lk[rr][c - D_STDC]; ka = srec * Lq[rr][c - D_STDC]; }
    Qa[row0 * D_DIM + i] = qa;
    Ka[row0 * D_DIM + i] = ka;
  }
}

// ---------------- flash attention over Q_aug/K_aug with key bias ----------------
// block = (b,h, q-tile of 64 rows), 256 threads.
// S-cols strided (tk+16j), O-cols contiguous (4tk+j): all hot LDS reads <=2-way.
__global__ __launch_bounds__(256, 2) void flash_kernel(
    const float* __restrict__ Qa, const float* __restrict__ Ka,
    const float* __restrict__ V, const float* __restrict__ dbias,
    const float* __restrict__ wdisc, float* __restrict__ Out)
{
  __shared__ __align__(16) float Qs[BQ][68];
  __shared__ __align__(16) float Ks[BK][68];
  __shared__ __align__(16) float Vs[BK][68];
  __shared__ __align__(16) float Ps[BQ][68];
  __shared__ float bs[BK];

  const int tid = threadIdx.x;
  const int bid = blockIdx.x;
  const int bh  = bid % BHC;
  const int qt  = NQT - 1 - (bid / BHC);   // heavy tiles dispatched first
  const int h   = bh % NH;
  const long base = (long)bh * T_SEQ * D_DIM;
  const int q0 = qt * BQ;

  { // stage Q tile (float4, 16B-aligned rows: 68*4=272B)
    const float4* Qg = (const float4*)(Qa + base + (long)q0 * D_DIM);
    for (int i = tid; i < BQ * D_DIM / 4; i += 256) {
      int rr = i >> 4, c4 = i & 15;
      *(float4*)&Qs[rr][c4 * 4] = Qg[i];
    }
  }
  const float wd = wdisc[h];

  const int tq = tid >> 4;   // q-group 0..15 (rows 4tq..4tq+3)
  const int tk = tid & 15;   // k-group 0..15

  float m_i[4], l_i[4], acc[4][4];
#pragma unroll
  for (int i = 0; i < 4; i++) {
    m_i[i] = -1e30f; l_i[i] = 0.f;
#pragma unroll
    for (int j = 0; j < 4; j++) acc[i][j] = 0.f;
  }

  for (int kt = 0; kt <= qt; kt++) {
    __syncthreads();  // previous iteration done with Ks/Vs/Ps (also covers Qs staging)
    const float4* Kg = (const float4*)(Ka + base + (long)kt * BK * D_DIM);
    const float4* Vg = (const float4*)(V  + base + (long)kt * BK * D_DIM);
    for (int i = tid; i < BK * D_DIM / 4; i += 256) {
      int rr = i >> 4, c4 = i & 15;
      *(float4*)&Ks[rr][c4 * 4] = Kg[i];
      *(float4*)&Vs[rr][c4 * 4] = Vg[i];
    }
    if (tid < BK) bs[tid] = wd * dbias[(long)bh * T_SEQ + kt * BK + tid];
    __syncthreads();

    // ---- S = Qa_tile · Ka_tile^T : rows 4tq+i, cols tk+16j ----
    float s[4][4];
#pragma unroll
    for (int i = 0; i < 4; i++)
#pragma unroll
      for (int j = 0; j < 4; j++) s[i][j] = 0.f;

#pragma unroll
    for (int d = 0; d < D_DIM; d += 4) {
      float4 qv[4], kv[4];
#pragma unroll
      for (int i = 0; i < 4; i++) qv[i] = *(const float4*)&Qs[4 * tq + i][d];
#pragma unroll
      for (int j = 0; j < 4; j++) kv[j] = *(const float4*)&Ks[tk + 16 * j][d];
#pragma unroll
      for (int i = 0; i < 4; i++)
#pragma unroll
        for (int j = 0; j < 4; j++)
          s[i][j] += qv[i].x * kv[j].x + qv[i].y * kv[j].y +
                     qv[i].z * kv[j].z + qv[i].w * kv[j].w;
    }

    // ---- scale + bias + causal mask ----
    const float scale = 0.125f;  // 1/sqrt(64)
    const bool diag = (kt == qt);
#pragma unroll
    for (int i = 0; i < 4; i++) {
      int qrow = q0 + 4 * tq + i;
#pragma unroll
      for (int j = 0; j < 4; j++) {
        int kcol = kt * BK + tk + 16 * j;
        float v = s[i][j] * scale + bs[tk + 16 * j];
        if (diag && kcol > qrow) v = -1e30f;
        s[i][j] = v;
      }
    }

    // ---- online softmax (row stats across the 16 tk-lanes) ----
#pragma unroll
    for (int i = 0; i < 4; i++) {
      float rowmax = fmaxf(fmaxf(s[i][0], s[i][1]), fmaxf(s[i][2], s[i][3]));
#pragma unroll
      for (int m = 1; m <= 8; m <<= 1) rowmax = fmaxf(rowmax, __shfl_xor(rowmax, m, 64));
      float mnew  = fmaxf(m_i[i], rowmax);
      float alpha = __expf(m_i[i] - mnew);
      float psum = 0.f;
#pragma unroll
      for (int j = 0; j < 4; j++) {
        float p = __expf(s[i][j] - mnew);
        s[i][j] = p;
        psum += p;
      }
#pragma unroll
      for (int m = 1; m <= 8; m <<= 1) psum += __shfl_xor(psum, m, 64);
      l_i[i] = l_i[i] * alpha + psum;
      m_i[i] = mnew;
#pragma unroll
      for (int j = 0; j < 4; j++) acc[i][j] *= alpha;
#pragma unroll
      for (int j = 0; j < 4; j++) Ps[4 * tq + i][tk + 16 * j] = s[i][j];
    }
    __syncthreads();

    // ---- O += P · V : O cols contiguous 4tk+j ----
#pragma unroll
    for (int k = 0; k < BK; k += 4) {
      float4 pv[4], vv[4];
#pragma unroll
      for (int i = 0; i < 4; i++) pv[i] = *(const float4*)&Ps[4 * tq + i][k];
#pragma unroll
      for (int kk = 0; kk < 4; kk++) vv[kk] = *(const float4*)&Vs[k + kk][4 * tk];
#pragma unroll
      for (int i = 0; i < 4; i++) {
        acc[i][0] += pv[i].x * vv[0].x + pv[i].y * vv[1].x + pv[i].z * vv[2].x + pv[i].w * vv[3].x;
        acc[i][1] += pv[i].x * vv[0].y + pv[i].y * vv[1].y + pv[i].z * vv[2].y + pv[i].w * vv[3].y;
        acc[i][2] += pv[i].x * vv[0].z + pv[i].y * vv[1].z + pv[i].z * vv[2].z + pv[i].w * vv[3].z;
        acc[i][3] += pv[i].x * vv[0].w + pv[i].y * vv[1].w + pv[i].z * vv[2].w + pv[i].w * vv[3].w;
      }
    }
  }

  // ---- epilogue: normalize and write (coalesced float4) ----
#pragma unroll
  for (int i = 0; i < 4; i++) {
    float inv = 1.f / l_i[i];
    float4 o;
    o.x = acc[i][0] * inv; o.y = acc[i][1] * inv;
    o.z = acc[i][2] * inv; o.w = acc[i][3] * inv;
    *(float4*)&Out[base + (long)(q0 + 4 * tq + i) * D_DIM + 4 * tk] = o;
  }
}

extern "C" void kernel_launch(void* const* d_in, const int* in_sizes, int n_in,
                              void* d_out, int out_size, void* d_ws, size_t ws_size,
                              hipStream_t stream) {
  const float* Q     = (const float*)d_in[0];
  const float* K     = (const float*)d_in[1];
  const float* V     = (const float*)d_in[2];
  const float* dbias = (const float*)d_in[3];
  const float* W     = (const float*)d_in[4];
  const float* wstd  = (const float*)d_in[5];
  const float* wrec  = (const float*)d_in[6];
  const float* wdisc = (const float*)d_in[7];
  float* Out = (float*)d_out;

  float* Qa = (float*)d_ws;                              // [BH,T,D] fp32, 12.6 MB
  float* Ka = Qa + (long)BHC * T_SEQ * D_DIM;            // [BH,T,D] fp32, 12.6 MB

  prep_kernel<<<BHC * T_SEQ / 64, 256, 0, stream>>>(Q, K, W, wstd, wrec, Qa, Ka);
  flash_kernel<<<BHC * NQT, 256, 0, stream>>>(Qa, Ka, V, dbias, wdisc, Out);
}

// Round 2
// 200.548 us; speedup vs baseline: 1.8752x; 1.8752x over previous
//
#include <hip/hip_runtime.h>
#include <math.h>

#define T_SEQ 2048
#define NH    12
#define NB    2
#define BHC   (NB*NH)        // 24
#define D_DIM 64
#define R_DIM 16
#define D_STDC 48
#define BQ    64
#define BK    64
#define NQT   (T_SEQ/BQ)     // 32
#define SK    72             // LDS row stride (bf16 elems): 144B, 16B-aligned, <=2-way banks

typedef short  short8  __attribute__((ext_vector_type(8)));
typedef float  floatx4 __attribute__((ext_vector_type(4)));

__device__ __forceinline__ ushort f2bf(float x) {  // RNE float->bf16
  unsigned u = __float_as_uint(x);
  u += 0x7fffu + ((u >> 16) & 1u);
  return (ushort)(u >> 16);
}

// ---------------- prep: bf16 Q_aug (scale folded), bf16 K_aug, bf16 V^T ----------------
__global__ __launch_bounds__(256) void prep_kernel(
    const float* __restrict__ Q, const float* __restrict__ K,
    const float* __restrict__ V, const float* __restrict__ W,
    const float* __restrict__ wstd, const float* __restrict__ wrec,
    ushort* __restrict__ Qa, ushort* __restrict__ Ka, ushort* __restrict__ Vt)
{
  __shared__ float Ws[D_DIM][R_DIM];
  __shared__ float Qs[64][65];
  __shared__ float Ksh[64][65];
  __shared__ float Vs[64][65];
  __shared__ float Lq[64][R_DIM];
  __shared__ float Lk[64][R_DIM];

  const int tid = threadIdx.x;
  const long row0 = (long)blockIdx.x * 64;      // flat (b,h,t) row
  const int bh = (int)(row0 / T_SEQ);
  const int h  = bh % NH;
  const int t0 = (int)(row0 % T_SEQ);

  for (int i = tid; i < D_DIM * R_DIM; i += 256) Ws[i / R_DIM][i % R_DIM] = W[i];
  for (int i = tid; i < 64 * D_DIM; i += 256) {
    int r = i >> 6, c = i & 63;
    Qs[r][c]  = Q[row0 * D_DIM + i];
    Ksh[r][c] = K[row0 * D_DIM + i];
    Vs[r][c]  = V[row0 * D_DIM + i];
  }
  __syncthreads();

  // low-rank projections: each row by 4 threads, 16-wide d-slices
  const int r = tid >> 2, part = tid & 3;
  float ql[R_DIM], kl[R_DIM];
#pragma unroll
  for (int j = 0; j < R_DIM; j++) { ql[j] = 0.f; kl[j] = 0.f; }
#pragma unroll
  for (int dd = 0; dd < 16; dd++) {
    int d = part * 16 + dd;
    float qv = Qs[r][d], kv = Ksh[r][d];
#pragma unroll
    for (int j = 0; j < R_DIM; j++) { ql[j] += qv * Ws[d][j]; kl[j] += kv * Ws[d][j]; }
  }
#pragma unroll
  for (int m = 1; m <= 2; m <<= 1) {
#pragma unroll
    for (int j = 0; j < R_DIM; j++) {
      ql[j] += __shfl_xor(ql[j], m, 64);
      kl[j] += __shfl_xor(kl[j], m, 64);
    }
  }
  if (part == 0) {
#pragma unroll
    for (int j = 0; j < R_DIM; j++) { Lq[r][j] = ql[j]; Lk[r][j] = kl[j]; }
  }
  __syncthreads();

  const float sstd = sqrtf(wstd[h]);
  const float srec = sqrtf(wrec[h]);
  const float qsc  = 0.125f;  // 1/sqrt(64) folded into Q_aug

  uint* Qa32 = (uint*)(Qa + row0 * D_DIM);
  uint* Ka32 = (uint*)(Ka + row0 * D_DIM);
  for (int i = tid; i < 64 * D_DIM / 2; i += 256) {   // packed 2xbf16 stores
    int rr = i >> 5, c = (i & 31) * 2;
    float qa0, ka0, qa1, ka1;
    if (c < D_STDC) { qa0 = sstd * Qs[rr][c];  ka0 = sstd * Ksh[rr][c]; }
    else            { qa0 = srec * Lk[rr][c - D_STDC]; ka0 = srec * Lq[rr][c - D_STDC]; }
    int c1 = c + 1;
    if (c1 < D_STDC){ qa1 = sstd * Qs[rr][c1]; ka1 = sstd * Ksh[rr][c1]; }
    else            { qa1 = srec * Lk[rr][c1 - D_STDC]; ka1 = srec * Lq[rr][c1 - D_STDC]; }
    Qa32[i] = (uint)f2bf(qa0 * qsc) | ((uint)f2bf(qa1 * qsc) << 16);
    Ka32[i] = (uint)f2bf(ka0)       | ((uint)f2bf(ka1) << 16);
  }
  // V^T: Vt[bh][d][t], per-d rows of 64 t-values (coalesced 128B runs)
  for (int i = tid; i < 64 * 32; i += 256) {
    int d = i >> 5, tp = (i & 31) * 2;
    uint v = (uint)f2bf(Vs[tp][d]) | ((uint)f2bf(Vs[tp + 1][d]) << 16);
    *(uint*)(Vt + (long)bh * D_DIM * T_SEQ + (long)d * T_SEQ + t0 + tp) = v;
  }
}

// ---------------- flash attention, bf16 MFMA 16x16x32 ----------------
__global__ __launch_bounds__(256) void flash_kernel(
    const ushort* __restrict__ Qa, const ushort* __restrict__ Ka,
    const ushort* __restrict__ Vt, const float* __restrict__ dbias,
    const float* __restrict__ wdisc, float* __restrict__ Out)
{
  __shared__ ushort KsL[64 * SK];      // K_aug tile [key][d]
  __shared__ ushort VsL[64 * SK];      // V^T tile [d][key]
  __shared__ ushort Ps[4][16 * SK];    // per-wave P [qrow][key]
  __shared__ float  bs[64];

  const int tid  = threadIdx.x;
  const int w    = tid >> 6, lane = tid & 63;
  const int quad = lane >> 4, ln = lane & 15;
  const int bid  = blockIdx.x;
  const int bh   = bid % BHC;
  const int qt   = NQT - 1 - bid / BHC;   // heavy tiles first
  const int h    = bh % NH;
  const int q0   = qt * BQ;
  const long base = (long)bh * T_SEQ * D_DIM;

  // Q A-fragments (held in registers for the whole K-loop); rows q0+16w+ln
  short8 qf[2];
  {
    const ushort* qrow = Qa + base + (long)(q0 + 16 * w + ln) * D_DIM + quad * 8;
    qf[0] = *(const short8*)(qrow);
    qf[1] = *(const short8*)(qrow + 32);
  }
  const float wd = wdisc[h];

  float m_i[4], l_i[4];
  floatx4 acc[4];
#pragma unroll
  for (int i = 0; i < 4; i++) {
    m_i[i] = -1e30f; l_i[i] = 0.f;
    acc[i] = (floatx4){0.f, 0.f, 0.f, 0.f};
  }

  for (int kt = 0; kt <= qt; kt++) {
    __syncthreads();   // all waves done reading previous Ks/Vs
    {
      const int4* gK = (const int4*)(Ka + base + (long)kt * BK * D_DIM);
      for (int i = tid; i < 512; i += 256) {
        int rr = i >> 3, c8 = i & 7;
        *(int4*)&KsL[rr * SK + c8 * 8] = gK[i];
      }
      const ushort* gV = Vt + (long)bh * D_DIM * T_SEQ + kt * BK;
      for (int i = tid; i < 512; i += 256) {
        int d = i >> 3, c8 = i & 7;
        *(int4*)&VsL[d * SK + c8 * 8] = *(const int4*)(gV + (long)d * T_SEQ + c8 * 8);
      }
      if (tid < 64) bs[tid] = wd * dbias[(long)bh * T_SEQ + kt * BK + tid];
    }
    __syncthreads();

    // ---- S = Qa · Ka^T (scale pre-folded into Qa) ----
    floatx4 sc[4];
#pragma unroll
    for (int nt = 0; nt < 4; nt++) sc[nt] = (floatx4){0.f, 0.f, 0.f, 0.f};
#pragma unroll
    for (int ks = 0; ks < 2; ks++) {
      short8 a = qf[ks];
#pragma unroll
      for (int nt = 0; nt < 4; nt++) {
        short8 b = *(const short8*)&KsL[(nt * 16 + ln) * SK + ks * 32 + quad * 8];
        sc[nt] = __builtin_amdgcn_mfma_f32_16x16x32_bf16(a, b, sc[nt], 0, 0, 0);
      }
    }

    // ---- bias + causal mask + online softmax (C layout: row=quad*4+r, col=ln) ----
    const bool diag = (kt == qt);
#pragma unroll
    for (int r = 0; r < 4; r++) {
      const int qrow = q0 + 16 * w + quad * 4 + r;
      float sv[4];
#pragma unroll
      for (int nt = 0; nt < 4; nt++) {
        int kcol = kt * BK + nt * 16 + ln;
        float v = sc[nt][r] + bs[nt * 16 + ln];
        sv[nt] = (diag && kcol > qrow) ? -1e30f : v;
      }
      float rowmax = fmaxf(fmaxf(sv[0], sv[1]), fmaxf(sv[2], sv[3]));
#pragma unroll
      for (int m = 1; m <= 8; m <<= 1) rowmax = fmaxf(rowmax, __shfl_xor(rowmax, m, 64));
      float mnew  = fmaxf(m_i[r], rowmax);
      float alpha = __expf(m_i[r] - mnew);
      float psum = 0.f;
#pragma unroll
      for (int nt = 0; nt < 4; nt++) { float p = __expf(sv[nt] - mnew); sv[nt] = p; psum += p; }
#pragma unroll
      for (int m = 1; m <= 8; m <<= 1) psum += __shfl_xor(psum, m, 64);
      l_i[r] = l_i[r] * alpha + psum;
      m_i[r] = mnew;
#pragma unroll
      for (int nt = 0; nt < 4; nt++) acc[nt][r] *= alpha;
#pragma unroll
      for (int nt = 0; nt < 4; nt++)
        Ps[w][(quad * 4 + r) * SK + nt * 16 + ln] = f2bf(sv[nt]);
    }

    // ---- O += P · V (P wave-private: no barrier; compiler inserts lgkmcnt) ----
#pragma unroll
    for (int ks = 0; ks < 2; ks++) {
      short8 a = *(const short8*)&Ps[w][ln * SK + ks * 32 + quad * 8];
#pragma unroll
      for (int nt = 0; nt < 4; nt++) {
        short8 b = *(const short8*)&VsL[(nt * 16 + ln) * SK + ks * 32 + quad * 8];
        acc[nt] = __builtin_amdgcn_mfma_f32_16x16x32_bf16(a, b, acc[nt], 0, 0, 0);
      }
    }
  }

  // ---- epilogue ----
#pragma unroll
  for (int r = 0; r < 4; r++) {
    float inv = 1.f / l_i[r];
    const long orow = base + (long)(q0 + 16 * w + quad * 4 + r) * D_DIM;
#pragma unroll
    for (int nt = 0; nt < 4; nt++)
      Out[orow + nt * 16 + ln] = acc[nt][r] * inv;
  }
}

extern "C" void kernel_launch(void* const* d_in, const int* in_sizes, int n_in,
                              void* d_out, int out_size, void* d_ws, size_t ws_size,
                              hipStream_t stream) {
  const float* Q     = (const float*)d_in[0];
  const float* K     = (const float*)d_in[1];
  const float* V     = (const float*)d_in[2];
  const float* dbias = (const float*)d_in[3];
  const float* W     = (const float*)d_in[4];
  const float* wstd  = (const float*)d_in[5];
  const float* wrec  = (const float*)d_in[6];
  const float* wdisc = (const float*)d_in[7];
  float* Out = (float*)d_out;

  const long NEL = (long)BHC * T_SEQ * D_DIM;   // 3,145,728 elems per tensor
  ushort* Qa = (ushort*)d_ws;        // bf16 [bh][t][d], scale folded
  ushort* Ka = Qa + NEL;             // bf16 [bh][t][d]
  ushort* Vt = Ka + NEL;             // bf16 [bh][d][t]

  prep_kernel<<<BHC * T_SEQ / 64, 256, 0, stream>>>(Q, K, V, W, wstd, wrec, Qa, Ka, Vt);
  flash_kernel<<<BHC * NQT, 256, 0, stream>>>(Qa, Ka, Vt, dbias, wdisc, Out);
}

// Round 3
// 145.832 us; speedup vs baseline: 2.5788x; 1.3752x over previous
//
#include <hip/hip_runtime.h>
#include <math.h>

#define T_SEQ 2048
#define NH    12
#define NB    2
#define BHC   (NB*NH)        // 24
#define NQT   32             // 2048/64

typedef _Float16 half4_t __attribute__((ext_vector_type(4)));
typedef _Float16 half8_t __attribute__((ext_vector_type(8)));
typedef float    floatx4 __attribute__((ext_vector_type(4)));

__device__ __forceinline__ void async_cp16(const void* g, void* l) {
  __builtin_amdgcn_global_load_lds((const __attribute__((address_space(1))) void*)g,
                                   (__attribute__((address_space(3))) void*)l, 16, 0, 0);
}
__device__ __forceinline__ void async_cp4(const void* g, void* l) {
  __builtin_amdgcn_global_load_lds((const __attribute__((address_space(1))) void*)g,
                                   (__attribute__((address_space(3))) void*)l, 4, 0, 0);
}

// ---------------- prep: f16 fragment-order Q_aug / K_aug / V ----------------
// QF/KF chunk (tile16, dp, lane): row = tile16*16 + ln, d = dp*32 + quad*4 + {0..3, 16..19}
// VF chunk (tile64, v2, nt, lane): d = nt*16 + ln, key = tile64*64 + v2*32 + quad*4 + {0..3, 16..19}
__global__ __launch_bounds__(256) void prep_kernel(
    const float* __restrict__ Q, const float* __restrict__ K,
    const float* __restrict__ V, const float* __restrict__ W,
    const float* __restrict__ wstd, const float* __restrict__ wrec,
    ushort* __restrict__ QF, ushort* __restrict__ KF, ushort* __restrict__ VF)
{
  __shared__ __align__(16) float Qs[64*72];   // stride 72 f32 = 288B (16B-aligned)
  __shared__ __align__(16) float Ks[64*72];
  __shared__ __align__(16) float Vs[64*72];
  __shared__ __align__(16) float Lq[64*20];   // stride 20 f32 = 80B (16B-aligned)
  __shared__ __align__(16) float Lk[64*20];

  const int tid = threadIdx.x;
  const int w = tid >> 6, lane = tid & 63;
  const int quad = lane >> 4, ln = lane & 15;
  const int bh = blockIdx.x >> 5;
  const int tblk = blockIdx.x & 31;
  const long g0 = ((long)bh * T_SEQ + tblk * 64) * 64;

  const float4* gQ = (const float4*)(Q + g0);
  const float4* gK = (const float4*)(K + g0);
  const float4* gV = (const float4*)(V + g0);
  for (int i = tid; i < 1024; i += 256) {
    int r = i >> 4, c = i & 15;
    *(float4*)&Qs[r*72 + c*4] = gQ[i];
    *(float4*)&Ks[r*72 + c*4] = gK[i];
    *(float4*)&Vs[r*72 + c*4] = gV[i];
  }
  __syncthreads();

  // W B-frags straight from global (L2-resident, 4KB)
  half4_t bw[4];
#pragma unroll
  for (int dk = 0; dk < 4; dk++)
#pragma unroll
    for (int i = 0; i < 4; i++)
      bw[dk][i] = (_Float16)W[(dk*16 + quad*4 + i)*16 + ln];

  // Q_low = Q·W, K_low = K·W via MFMA (wave w owns rows 16w..16w+15)
  floatx4 cq = {0.f,0.f,0.f,0.f}, ck = {0.f,0.f,0.f,0.f};
#pragma unroll
  for (int dk = 0; dk < 4; dk++) {
    half4_t aq, ak;
#pragma unroll
    for (int i = 0; i < 4; i++) {
      aq[i] = (_Float16)Qs[(w*16 + ln)*72 + dk*16 + quad*4 + i];
      ak[i] = (_Float16)Ks[(w*16 + ln)*72 + dk*16 + quad*4 + i];
    }
    cq = __builtin_amdgcn_mfma_f32_16x16x16f16(aq, bw[dk], cq, 0, 0, 0);
    ck = __builtin_amdgcn_mfma_f32_16x16x16f16(ak, bw[dk], ck, 0, 0, 0);
  }
#pragma unroll
  for (int i = 0; i < 4; i++) {            // C: row = 16w+quad*4+i, col(r) = ln
    Lq[(w*16 + quad*4 + i)*20 + ln] = cq[i];
    Lk[(w*16 + quad*4 + i)*20 + ln] = ck[i];
  }
  __syncthreads();

  const int h = bh % NH;
  const float sstd = sqrtf(wstd[h]);
  const float srec = sqrtf(wrec[h]);
  const float qsc  = 0.125f;   // 1/sqrt(64) folded into Q_aug

#pragma unroll
  for (int cc = 0; cc < 2; cc++) {
    int c = tid + cc*256;                  // chunk 0..511, tid-consecutive stores
    // ---- QF / KF ----
    {
      int lp = c & 63, dp = (c >> 6) & 1, rt = c >> 7;
      int lnp = lp & 15, qp = lp >> 4;
      int row = rt*16 + lnp;
      half8_t hq, hk;
#pragma unroll
      for (int uu = 0; uu < 2; uu++) {
        int d0 = dp*32 + uu*16 + qp*4;
        if (d0 < 48) {
#pragma unroll
          for (int j = 0; j < 4; j++) {
            hq[uu*4+j] = (_Float16)(qsc*sstd*Qs[row*72 + d0 + j]);
            hk[uu*4+j] = (_Float16)(sstd*Ks[row*72 + d0 + j]);
          }
        } else {
#pragma unroll
          for (int j = 0; j < 4; j++) {
            hq[uu*4+j] = (_Float16)(qsc*srec*Lk[row*20 + d0-48 + j]);  // Q_aug gets K_low
            hk[uu*4+j] = (_Float16)(srec*Lq[row*20 + d0-48 + j]);      // K_aug gets Q_low
          }
        }
      }
      long tile16 = (long)bh*128 + tblk*4 + rt;
      ((int4*)QF)[tile16*128 + dp*64 + lp] = *(int4*)&hq;
      ((int4*)KF)[tile16*128 + dp*64 + lp] = *(int4*)&hk;
    }
    // ---- VF ----
    {
      int lv = c & 63, nt = (c >> 6) & 3, v2 = c >> 8;
      int lnv = lv & 15, qv = lv >> 4;
      int d = nt*16 + lnv;
      half8_t hv;
#pragma unroll
      for (int j = 0; j < 4; j++) {
        hv[j]   = (_Float16)Vs[(v2*32 + qv*4 + j)*72 + d];
        hv[4+j] = (_Float16)Vs[(v2*32 + 16 + qv*4 + j)*72 + d];
      }
      long t64 = (long)bh*32 + tblk;
      ((int4*)VF)[t64*512 + (v2*4 + nt)*64 + lv] = *(int4*)&hv;
    }
  }
}

// ---------------- flash: S^T trick, zero-conflict frag reads ----------------
__global__ __launch_bounds__(256) void flash_kernel(
    const ushort* __restrict__ QF, const ushort* __restrict__ KF,
    const ushort* __restrict__ VF, const float* __restrict__ dbias,
    const float* __restrict__ wdisc, float* __restrict__ Out)
{
  __shared__ __align__(16) ushort KsL[4096];   // 8KB, fragment order
  __shared__ __align__(16) ushort VsL[4096];   // 8KB, fragment order
  __shared__ float bs[64];

  const int tid = threadIdx.x;
  const int w = tid >> 6, lane = tid & 63;
  const int quad = lane >> 4, ln = lane & 15;
  const int bid = blockIdx.x;
  const int bh = bid % BHC;                 // same bh -> same XCD (24 % 8 == 0)
  const int qt = NQT - 1 - bid / BHC;       // heavy tiles first
  const int h = bh % NH;
  const int q0 = qt * 64;
  const int qrow = q0 + w*16 + ln;          // this lane's q-row
  const float wd = wdisc[h];

  // Q B-frags for the whole K-loop (lane-contiguous b128 global loads)
  half4_t bq[4];
  {
    const ushort* gQ = QF + ((long)bh*128 + qt*4 + w) * 1024;
    half8_t q01 = *(const half8_t*)(gQ + lane*8);
    half8_t q23 = *(const half8_t*)(gQ + 512 + lane*8);
    bq[0] = __builtin_shufflevector(q01, q01, 0,1,2,3);
    bq[1] = __builtin_shufflevector(q01, q01, 4,5,6,7);
    bq[2] = __builtin_shufflevector(q23, q23, 0,1,2,3);
    bq[3] = __builtin_shufflevector(q23, q23, 4,5,6,7);
  }

  float m_i = -1e30f, l_i = 0.f;
  floatx4 acc[4];
#pragma unroll
  for (int nt = 0; nt < 4; nt++) acc[nt] = (floatx4){0.f,0.f,0.f,0.f};

  for (int kt = 0; kt <= qt; kt++) {
    __syncthreads();   // previous tile's LDS reads complete
    {
      const ushort* gK = KF + ((long)bh*256 + (long)kt*8) * 512;
      const ushort* gV = VF + ((long)bh*256 + (long)kt*8) * 512;
      for (int c = w; c < 8; c += 4) {
        async_cp16(gK + c*512 + lane*8, &KsL[c*512]);   // dest = base + lane*16
        async_cp16(gV + c*512 + lane*8, &VsL[c*512]);
      }
      if (w == 0) async_cp4(dbias + (long)bh*T_SEQ + kt*64 + lane, bs);
    }
    __syncthreads();   // compiler drains vmcnt(0) before s_barrier

    // ---- S^T = K_aug · Q_aug^T : st[mt] reg i = S[q=ln][key=kt*64+mt*16+quad*4+i]
    floatx4 st[4];
#pragma unroll
    for (int mt = 0; mt < 4; mt++) st[mt] = (floatx4){0.f,0.f,0.f,0.f};
#pragma unroll
    for (int mt = 0; mt < 4; mt++) {
#pragma unroll
      for (int dp = 0; dp < 2; dp++) {
        half8_t kk = *(const half8_t*)&KsL[(mt*2 + dp)*512 + lane*8];  // lane-contiguous
        half4_t a0 = __builtin_shufflevector(kk, kk, 0,1,2,3);
        half4_t a1 = __builtin_shufflevector(kk, kk, 4,5,6,7);
        st[mt] = __builtin_amdgcn_mfma_f32_16x16x16f16(a0, bq[2*dp],   st[mt], 0, 0, 0);
        st[mt] = __builtin_amdgcn_mfma_f32_16x16x16f16(a1, bq[2*dp+1], st[mt], 0, 0, 0);
      }
    }

    // ---- bias + causal mask + online softmax (one q-row per lane) ----
    const bool diag = (kt == qt);
    float rowmax = -1e30f;
#pragma unroll
    for (int mt = 0; mt < 4; mt++)
#pragma unroll
      for (int i = 0; i < 4; i++) {
        float v = st[mt][i] + wd * bs[mt*16 + quad*4 + i];   // broadcast read
        int key = kt*64 + mt*16 + quad*4 + i;
        if (diag && key > qrow) v = -1e30f;
        st[mt][i] = v;
        rowmax = fmaxf(rowmax, v);
      }
    rowmax = fmaxf(rowmax, __shfl_xor(rowmax, 16));
    rowmax = fmaxf(rowmax, __shfl_xor(rowmax, 32));
    float mnew  = fmaxf(m_i, rowmax);
    float alpha = __expf(m_i - mnew);
    float psum = 0.f;
    half4_t pa[4];                       // C-regs become PV A-operand directly
#pragma unroll
    for (int mt = 0; mt < 4; mt++)
#pragma unroll
      for (int i = 0; i < 4; i++) {
        float p = __expf(st[mt][i] - mnew);
        psum += p;
        pa[mt][i] = (_Float16)p;
      }
    psum += __shfl_xor(psum, 16);
    psum += __shfl_xor(psum, 32);
    l_i = l_i * alpha + psum;
    m_i = mnew;

    // alpha lives at lane ln=q; acc rows are quad*4+i -> broadcast
    float af[4];
#pragma unroll
    for (int i = 0; i < 4; i++) af[i] = __shfl(alpha, quad*4 + i);
#pragma unroll
    for (int nt = 0; nt < 4; nt++)
#pragma unroll
      for (int i = 0; i < 4; i++) acc[nt][i] *= af[i];

    // ---- O += P · V ----
#pragma unroll
    for (int v2 = 0; v2 < 2; v2++)
#pragma unroll
      for (int nt = 0; nt < 4; nt++) {
        half8_t vv = *(const half8_t*)&VsL[(v2*4 + nt)*512 + lane*8];  // lane-contiguous
        half4_t b0 = __builtin_shufflevector(vv, vv, 0,1,2,3);
        half4_t b1 = __builtin_shufflevector(vv, vv, 4,5,6,7);
        acc[nt] = __builtin_amdgcn_mfma_f32_16x16x16f16(pa[2*v2],   b0, acc[nt], 0, 0, 0);
        acc[nt] = __builtin_amdgcn_mfma_f32_16x16x16f16(pa[2*v2+1], b1, acc[nt], 0, 0, 0);
      }
  }

  // ---- epilogue ----
  float lr[4];
#pragma unroll
  for (int i = 0; i < 4; i++) lr[i] = 1.f / __shfl(l_i, quad*4 + i);
  const long obase = (long)bh*T_SEQ*64 + (long)(q0 + w*16)*64;
#pragma unroll
  for (int i = 0; i < 4; i++)
#pragma unroll
    for (int nt = 0; nt < 4; nt++)
      Out[obase + (quad*4 + i)*64 + nt*16 + ln] = acc[nt][i] * lr[i];
}

extern "C" void kernel_launch(void* const* d_in, const int* in_sizes, int n_in,
                              void* d_out, int out_size, void* d_ws, size_t ws_size,
                              hipStream_t stream) {
  const float* Q     = (const float*)d_in[0];
  const float* K     = (const float*)d_in[1];
  const float* V     = (const float*)d_in[2];
  const float* dbias = (const float*)d_in[3];
  const float* W     = (const float*)d_in[4];
  const float* wstd  = (const float*)d_in[5];
  const float* wrec  = (const float*)d_in[6];
  const float* wdisc = (const float*)d_in[7];
  float* Out = (float*)d_out;

  const long NEL = (long)BHC * T_SEQ * 64;   // 3,145,728 halves per tensor
  ushort* QF = (ushort*)d_ws;                // f16 fragment-order Q_aug (scale folded)
  ushort* KF = QF + NEL;                     // f16 fragment-order K_aug
  ushort* VF = KF + NEL;                     // f16 fragment-order V

  prep_kernel<<<BHC * NQT, 256, 0, stream>>>(Q, K, V, W, wstd, wrec, QF, KF, VF);
  flash_kernel<<<BHC * NQT, 256, 0, stream>>>(QF, KF, VF, dbias, wdisc, Out);
}

// Round 4
// 142.008 us; speedup vs baseline: 2.6483x; 1.0269x over previous
//
#include <hip/hip_runtime.h>
#include <math.h>

#define T_SEQ 2048
#define NH    12
#define NB    2
#define BHC   (NB*NH)        // 24
#define NQT   32             // 2048/64

typedef _Float16 half4_t __attribute__((ext_vector_type(4)));
typedef _Float16 half8_t __attribute__((ext_vector_type(8)));
typedef float    floatx4 __attribute__((ext_vector_type(4)));

__device__ __forceinline__ void async_cp16(const void* g, void* l) {
  __builtin_amdgcn_global_load_lds((const __attribute__((address_space(1))) void*)g,
                                   (__attribute__((address_space(3))) void*)l, 16, 0, 0);
}
__device__ __forceinline__ void async_cp4(const void* g, void* l) {
  __builtin_amdgcn_global_load_lds((const __attribute__((address_space(1))) void*)g,
                                   (__attribute__((address_space(3))) void*)l, 4, 0, 0);
}
__device__ __forceinline__ half8_t h8splat(_Float16 s) {
  return (half8_t){s, s, s, s, s, s, s, s};
}

// ---------------- prep ----------------
// QF/KF chunk (tile16, dp, lane): row = tile16*16 + ln, d = dp*32 + quad*8 + j  (x32 frag order)
// VF chunk (tile64, v2, nt, lane): d = nt*16 + ln, key = tile64*64 + v2*32 + quad*4 + {j, 16+j} (x16)
__global__ __launch_bounds__(256) void prep_kernel(
    const float* __restrict__ Q, const float* __restrict__ K,
    const float* __restrict__ V, const float* __restrict__ W,
    const float* __restrict__ wstd, const float* __restrict__ wrec,
    ushort* __restrict__ QF, ushort* __restrict__ KF, ushort* __restrict__ VF)
{
  __shared__ __align__(16) _Float16 Qsh[64*72];   // 144B row stride
  __shared__ __align__(16) _Float16 Ksh[64*72];
  __shared__ __align__(16) _Float16 Vsh[64*72];
  __shared__ __align__(16) _Float16 Lqh[64*16];
  __shared__ __align__(16) _Float16 Lkh[64*16];

  const int tid = threadIdx.x;
  const int w = tid >> 6, lane = tid & 63;
  const int quad = lane >> 4, ln = lane & 15;
  const int bh = blockIdx.x >> 5, tblk = blockIdx.x & 31;
  const long g0 = ((long)bh * T_SEQ + tblk * 64) * 64;

  const float4* gQ = (const float4*)(Q + g0);
  const float4* gK = (const float4*)(K + g0);
  const float4* gV = (const float4*)(V + g0);
  for (int i = tid; i < 1024; i += 256) {
    int r = i >> 4, c4 = i & 15;
    float4 q = gQ[i], k = gK[i], v = gV[i];
    *(half4_t*)&Qsh[r*72 + c4*4] = (half4_t){(_Float16)q.x,(_Float16)q.y,(_Float16)q.z,(_Float16)q.w};
    *(half4_t*)&Ksh[r*72 + c4*4] = (half4_t){(_Float16)k.x,(_Float16)k.y,(_Float16)k.z,(_Float16)k.w};
    *(half4_t*)&Vsh[r*72 + c4*4] = (half4_t){(_Float16)v.x,(_Float16)v.y,(_Float16)v.z,(_Float16)v.w};
  }
  __syncthreads();

  // W B-frags from global (4KB, L2-resident)
  half4_t bw[4];
#pragma unroll
  for (int dk = 0; dk < 4; dk++)
#pragma unroll
    for (int i = 0; i < 4; i++)
      bw[dk][i] = (_Float16)W[(dk*16 + quad*4 + i)*16 + ln];

  // Q_low = Q·W, K_low = K·W via MFMA (wave w owns rows 16w..16w+15)
  floatx4 cq = {0.f,0.f,0.f,0.f}, ck = {0.f,0.f,0.f,0.f};
#pragma unroll
  for (int dk = 0; dk < 4; dk++) {
    half4_t aq = *(const half4_t*)&Qsh[(w*16 + ln)*72 + dk*16 + quad*4];
    half4_t ak = *(const half4_t*)&Ksh[(w*16 + ln)*72 + dk*16 + quad*4];
    cq = __builtin_amdgcn_mfma_f32_16x16x16f16(aq, bw[dk], cq, 0, 0, 0);
    ck = __builtin_amdgcn_mfma_f32_16x16x16f16(ak, bw[dk], ck, 0, 0, 0);
  }
#pragma unroll
  for (int i = 0; i < 4; i++) {            // C: row = 16w+quad*4+i, col = ln
    Lqh[(w*16 + quad*4 + i)*16 + ln] = (_Float16)cq[i];
    Lkh[(w*16 + quad*4 + i)*16 + ln] = (_Float16)ck[i];
  }
  __syncthreads();

  const int h = bh % NH;
  const float sstd = sqrtf(wstd[h]);
  const float srec = sqrtf(wrec[h]);
  const half8_t hq_std = h8splat((_Float16)(0.125f * sstd));  // 1/sqrt(64) folded into Q
  const half8_t hk_std = h8splat((_Float16)sstd);
  const half8_t hq_rec = h8splat((_Float16)(0.125f * srec));
  const half8_t hk_rec = h8splat((_Float16)srec);

#pragma unroll
  for (int cc = 0; cc < 2; cc++) {
    int c = tid + cc * 256;                // chunk 0..511
    // ---- QF / KF (x32 frag order, pure b128 LDS reads) ----
    {
      int lp = c & 63, dp = (c >> 6) & 1, rt = c >> 7;
      int row = rt*16 + (lp & 15);
      int d0 = dp*32 + (lp >> 4)*8;        // {0,8,...,56}; 48-boundary on chunk boundary
      half8_t hq, hk;
      if (d0 < 48) {
        hq = *(const half8_t*)&Qsh[row*72 + d0] * hq_std;
        hk = *(const half8_t*)&Ksh[row*72 + d0] * hk_std;
      } else {
        hq = *(const half8_t*)&Lkh[row*16 + (d0-48)] * hq_rec;  // Q_aug gets K_low
        hk = *(const half8_t*)&Lqh[row*16 + (d0-48)] * hk_rec;  // K_aug gets Q_low
      }
      long tile16 = (long)bh*128 + tblk*4 + rt;
      ((int4*)QF)[tile16*128 + dp*64 + lp] = *(int4*)&hq;
      ((int4*)KF)[tile16*128 + dp*64 + lp] = *(int4*)&hk;
    }
    // ---- VF (x16 frag order) ----
    {
      int lv = c & 63, nt = (c >> 6) & 3, v2 = c >> 8;
      int d = nt*16 + (lv & 15), qv = lv >> 4;
      half8_t hv;
#pragma unroll
      for (int j = 0; j < 4; j++) {
        hv[j]   = Vsh[(v2*32 + qv*4 + j)*72 + d];
        hv[4+j] = Vsh[(v2*32 + 16 + qv*4 + j)*72 + d];
      }
      ((int4*)VF)[((long)bh*32 + tblk)*512 + (v2*4 + nt)*64 + lv] = *(int4*)&hv;
    }
  }
}

// ---------------- flash: S^T trick + double-buffered async staging ----------------
__global__ __launch_bounds__(256) void flash_kernel(
    const ushort* __restrict__ QF, const ushort* __restrict__ KF,
    const ushort* __restrict__ VF, const float* __restrict__ dbias,
    const float* __restrict__ wdisc, float* __restrict__ Out)
{
  __shared__ __align__(16) ushort KsL[2][4096];   // ping-pong, frag order
  __shared__ __align__(16) ushort VsL[2][4096];
  __shared__ float bs[2][64];

  const int tid = threadIdx.x;
  const int w = tid >> 6, lane = tid & 63;
  const int quad = lane >> 4, ln = lane & 15;
  const int bid = blockIdx.x;
  const int bh = bid % BHC;                 // same bh -> same XCD (24 % 8 == 0)
  const int qt = NQT - 1 - bid / BHC;       // heavy tiles first
  const int h = bh % NH;
  const int q0 = qt * 64;
  const int qrow = q0 + w*16 + ln;          // this lane's q-row
  const float wd = wdisc[h];

  const ushort* gKb = KF + ((long)bh*256) * 512;
  const ushort* gVb = VF + ((long)bh*256) * 512;
  const float*  gB  = dbias + (long)bh*T_SEQ;

  // Q B-frags (x32 layout: d = quad*8+j per 32-slice), whole K-loop in regs
  half8_t bq[2];
  {
    const ushort* gQ = QF + ((long)bh*128 + qt*4 + w) * 1024;
    bq[0] = *(const half8_t*)(gQ + lane*8);
    bq[1] = *(const half8_t*)(gQ + 512 + lane*8);
  }

  float m_i = -1e30f, l_i = 0.f;
  floatx4 acc[4];
#pragma unroll
  for (int nt = 0; nt < 4; nt++) acc[nt] = (floatx4){0.f,0.f,0.f,0.f};

  // prologue: stage kt=0 into buffer 0
  {
    for (int c = w; c < 8; c += 4) {
      async_cp16(gKb + c*512 + lane*8, &KsL[0][c*512]);
      async_cp16(gVb + c*512 + lane*8, &VsL[0][c*512]);
    }
    if (w == 0) async_cp4(gB + lane, &bs[0][0]);
  }

  for (int kt = 0; kt <= qt; kt++) {
    const int cur = kt & 1;
    __syncthreads();   // drains vmcnt(0): buf[cur] loads (issued last iter) complete

    if (kt < qt) {     // prefetch kt+1 into the other buffer while computing
      const long o = (long)(kt + 1) * 8 * 512;
      for (int c = w; c < 8; c += 4) {
        async_cp16(gKb + o + c*512 + lane*8, &KsL[1-cur][c*512]);
        async_cp16(gVb + o + c*512 + lane*8, &VsL[1-cur][c*512]);
      }
      if (w == 0) async_cp4(gB + (kt+1)*64 + lane, &bs[1-cur][0]);
    }

    // ---- S^T = K_aug · Q_aug^T (x32): st[mt][i] = S[q=ln][key=kt*64+mt*16+quad*4+i]
    floatx4 st[4];
#pragma unroll
    for (int mt = 0; mt < 4; mt++) st[mt] = (floatx4){0.f,0.f,0.f,0.f};
#pragma unroll
    for (int mt = 0; mt < 4; mt++)
#pragma unroll
      for (int dp = 0; dp < 2; dp++) {
        half8_t a = *(const half8_t*)&KsL[cur][(mt*2 + dp)*512 + lane*8];
        st[mt] = __builtin_amdgcn_mfma_f32_16x16x32_f16(a, bq[dp], st[mt], 0, 0, 0);
      }

    // ---- bias + causal mask + online softmax (one q-row per lane) ----
    const bool diag = (kt == qt);
    float rowmax = -1e30f;
#pragma unroll
    for (int mt = 0; mt < 4; mt++)
#pragma unroll
      for (int i = 0; i < 4; i++) {
        float v = st[mt][i] + wd * bs[cur][mt*16 + quad*4 + i];
        int key = kt*64 + mt*16 + quad*4 + i;
        if (diag && key > qrow) v = -1e30f;
        st[mt][i] = v;
        rowmax = fmaxf(rowmax, v);
      }
    rowmax = fmaxf(rowmax, __shfl_xor(rowmax, 16));
    rowmax = fmaxf(rowmax, __shfl_xor(rowmax, 32));
    float mnew  = fmaxf(m_i, rowmax);
    float alpha = __expf(m_i - mnew);
    float psum = 0.f;
    half4_t pa[4];                        // C-regs are directly the x16 PV A-operand
#pragma unroll
    for (int mt = 0; mt < 4; mt++)
#pragma unroll
      for (int i = 0; i < 4; i++) {
        float p = __expf(st[mt][i] - mnew);
        psum += p;
        pa[mt][i] = (_Float16)p;
      }
    psum += __shfl_xor(psum, 16);
    psum += __shfl_xor(psum, 32);
    l_i = l_i * alpha + psum;
    m_i = mnew;

    float af[4];
#pragma unroll
    for (int i = 0; i < 4; i++) af[i] = __shfl(alpha, quad*4 + i);
#pragma unroll
    for (int nt = 0; nt < 4; nt++)
#pragma unroll
      for (int i = 0; i < 4; i++) acc[nt][i] *= af[i];

    // ---- O += P · V (x16; P never touches LDS) ----
#pragma unroll
    for (int v2 = 0; v2 < 2; v2++)
#pragma unroll
      for (int nt = 0; nt < 4; nt++) {
        half8_t vv = *(const half8_t*)&VsL[cur][(v2*4 + nt)*512 + lane*8];
        half4_t b0 = __builtin_shufflevector(vv, vv, 0,1,2,3);
        half4_t b1 = __builtin_shufflevector(vv, vv, 4,5,6,7);
        acc[nt] = __builtin_amdgcn_mfma_f32_16x16x16f16(pa[2*v2],   b0, acc[nt], 0, 0, 0);
        acc[nt] = __builtin_amdgcn_mfma_f32_16x16x16f16(pa[2*v2+1], b1, acc[nt], 0, 0, 0);
      }
  }

  // ---- epilogue ----
  float lr[4];
#pragma unroll
  for (int i = 0; i < 4; i++) lr[i] = 1.f / __shfl(l_i, quad*4 + i);
  const long obase = (long)bh*T_SEQ*64 + (long)(q0 + w*16)*64;
#pragma unroll
  for (int i = 0; i < 4; i++)
#pragma unroll
    for (int nt = 0; nt < 4; nt++)
      Out[obase + (quad*4 + i)*64 + nt*16 + ln] = acc[nt][i] * lr[i];
}

extern "C" void kernel_launch(void* const* d_in, const int* in_sizes, int n_in,
                              void* d_out, int out_size, void* d_ws, size_t ws_size,
                              hipStream_t stream) {
  const float* Q     = (const float*)d_in[0];
  const float* K     = (const float*)d_in[1];
  const float* V     = (const float*)d_in[2];
  const float* dbias = (const float*)d_in[3];
  const float* W     = (const float*)d_in[4];
  const float* wstd  = (const float*)d_in[5];
  const float* wrec  = (const float*)d_in[6];
  const float* wdisc = (const float*)d_in[7];
  float* Out = (float*)d_out;

  const long NEL = (long)BHC * T_SEQ * 64;
  ushort* QF = (ushort*)d_ws;    // f16 x32-frag-order Q_aug (scales folded)
  ushort* KF = QF + NEL;         // f16 x32-frag-order K_aug
  ushort* VF = KF + NEL;         // f16 x16-frag-order V

  prep_kernel<<<BHC * NQT, 256, 0, stream>>>(Q, K, V, W, wstd, wrec, QF, KF, VF);
  flash_kernel<<<BHC * NQT, 256, 0, stream>>>(QF, KF, VF, dbias, wdisc, Out);
}